// Round 1
// baseline (14778.050 us; speedup 1.0000x reference)
//
#include <hip/hip_runtime.h>
#include <hip/hip_bf16.h>
#include <cstddef>

// Problem constants
#define VOCAB 50000
#define D_EMB 512
#define HDIM  512
#define MDIM  512
#define BATCH 1024
#define SEQL  64
#define G4H   2048          // 4*H
#define ROWS  2048          // 2 inputs * BATCH
#define HC_LD 3088          // 3073 padded to multiple of 16 floats

__device__ __forceinline__ float sigf(float x) {
    return 1.0f / (1.0f + __expf(-x));
}
__device__ __forceinline__ float tanh_fast(float x) {
    x = fminf(30.0f, fmaxf(-30.0f, x));
    float t = __expf(-2.0f * x);
    return (1.0f - t) / (1.0f + t);
}

// ---------------------------------------------------------------------------
// Reorder weights so the 4 gates of cell n are adjacent columns:
// Wr[d][k][4*n+g] = K_d[k][g*512+n]
// ---------------------------------------------------------------------------
__global__ __launch_bounds__(256) void reorder_w(const float* __restrict__ kfw,
                                                 const float* __restrict__ kbw,
                                                 float* __restrict__ Wr) {
    int idx = blockIdx.x * 256 + threadIdx.x;
    if (idx >= 2 * 1024 * G4H) return;
    int d   = idx >> 21;               // 1024*2048 = 2^21
    int rem = idx & ((1 << 21) - 1);
    int k   = rem >> 11;
    int col = rem & 2047;
    int n = col >> 2, g = col & 3;
    const float* src = d ? kbw : kfw;
    Wr[idx] = src[k * G4H + g * 512 + n];
}

__global__ __launch_bounds__(256) void reorder_b(const float* __restrict__ bfw,
                                                 const float* __restrict__ bbw,
                                                 float* __restrict__ br) {
    int idx = blockIdx.x * 256 + threadIdx.x;
    if (idx >= 2 * G4H) return;
    int d = idx >> 11;
    int col = idx & 2047;
    int n = col >> 2, g = col & 3;
    const float* src = d ? bbw : bfw;
    br[idx] = src[g * 512 + n];
}

// ---------------------------------------------------------------------------
// One LSTM timestep, both directions (blockIdx.z), inputs batched (2048 rows).
// gates = [emb[tok] , h_in] @ Wr + br   then fused cell update.
// Tile: 128x128, BK=16, 256 threads, 8x8 per-thread micro-tile.
// ---------------------------------------------------------------------------
__global__ __launch_bounds__(256) void lstm_step(
    int t,
    const int* __restrict__ in1, const int* __restrict__ in2,
    const int* __restrict__ sl1, const int* __restrict__ sl2,
    const float* __restrict__ emb,
    const float* __restrict__ WrAll,   // [2][1024][2048]
    const float* __restrict__ brAll,   // [2][2048]
    const float* __restrict__ hinAll,  // [2][2048][512]
    float* __restrict__ houtAll,       // [2][2048][512]
    float* __restrict__ cAll)          // [2][2048][512]
{
    const int dir = blockIdx.z;
    const int bx = blockIdx.x;   // gate-col tile (0..15)
    const int by = blockIdx.y;   // row tile (0..15)
    const int tid = threadIdx.x;

    const float* W    = WrAll  + (size_t)dir * 1024 * G4H;
    const float* bias = brAll  + (size_t)dir * G4H;
    const float* h_in = hinAll + (size_t)dir * ROWS * HDIM;
    float* h_out      = houtAll + (size_t)dir * ROWS * HDIM;
    float* cbuf       = cAll    + (size_t)dir * ROWS * HDIM;

    __shared__ float As[16][136];
    __shared__ float Bs[16][128];
    __shared__ int   toks[128];
    __shared__ int   slens[128];

    if (tid < 128) {
        int r = by * 128 + tid;
        int b = r & (BATCH - 1);
        const int* inp = (r < BATCH) ? in1 : in2;
        int s = (r < BATCH) ? sl1[b] : sl2[b];
        int tt = t;
        if (dir == 1) tt = (t < s) ? (s - 1 - t) : t;
        toks[tid]  = inp[b * SEQL + tt];
        slens[tid] = s;
    }
    __syncthreads();

    float acc[8][8];
#pragma unroll
    for (int i = 0; i < 8; ++i)
#pragma unroll
        for (int j = 0; j < 8; ++j) acc[i][j] = 0.0f;

    const int tx = tid & 15, ty = tid >> 4;
    const int lr  = tid >> 1;          // A-load row 0..127
    const int ks  = (tid & 1) * 8;     // A-load k offset
    const int bkk = tid >> 4;          // B-load k row 0..15
    const int bns = (tid & 15) * 8;    // B-load col start

    for (int k0 = 0; k0 < 1024; k0 += 16) {
        // ---- stage A tile (gathered embedding rows for k<512, h for k>=512)
        const float* asrc;
        if (k0 < 512) {
            asrc = emb + (size_t)toks[lr] * D_EMB + (k0 + ks);
        } else {
            asrc = h_in + (size_t)(by * 128 + lr) * HDIM + (k0 - 512 + ks);
        }
        float4 a0 = *(const float4*)(asrc);
        float4 a1 = *(const float4*)(asrc + 4);
        As[ks + 0][lr] = a0.x; As[ks + 1][lr] = a0.y;
        As[ks + 2][lr] = a0.z; As[ks + 3][lr] = a0.w;
        As[ks + 4][lr] = a1.x; As[ks + 5][lr] = a1.y;
        As[ks + 6][lr] = a1.z; As[ks + 7][lr] = a1.w;

        // ---- stage B tile (reordered weights, coalesced)
        const float* bsrc = W + (size_t)(k0 + bkk) * G4H + bx * 128 + bns;
        float4 b0 = *(const float4*)(bsrc);
        float4 b1 = *(const float4*)(bsrc + 4);
        *(float4*)&Bs[bkk][bns]     = b0;
        *(float4*)&Bs[bkk][bns + 4] = b1;

        __syncthreads();

#pragma unroll
        for (int kk = 0; kk < 16; ++kk) {
            float a[8], b[8];
            *(float4*)(a)     = *(const float4*)&As[kk][ty * 8];
            *(float4*)(a + 4) = *(const float4*)&As[kk][ty * 8 + 4];
            *(float4*)(b)     = *(const float4*)&Bs[kk][tx * 8];
            *(float4*)(b + 4) = *(const float4*)&Bs[kk][tx * 8 + 4];
#pragma unroll
            for (int i = 0; i < 8; ++i)
#pragma unroll
                for (int j = 0; j < 8; ++j) acc[i][j] += a[i] * b[j];
        }
        __syncthreads();
    }

    // ---- fused LSTM cell epilogue: this block owns cells bx*32..bx*32+31
    float bcol[8];
    const int col0 = bx * 128 + tx * 8;
#pragma unroll
    for (int j = 0; j < 8; ++j) bcol[j] = bias[col0 + j];

#pragma unroll
    for (int i = 0; i < 8; ++i) {
        int rl = ty * 8 + i;
        int r = by * 128 + rl;
        bool act = (t < slens[rl]);
#pragma unroll
        for (int jc = 0; jc < 2; ++jc) {
            float gi = acc[i][jc * 4 + 0] + bcol[jc * 4 + 0];
            float gj = acc[i][jc * 4 + 1] + bcol[jc * 4 + 1];
            float gf = acc[i][jc * 4 + 2] + bcol[jc * 4 + 2];
            float go = acc[i][jc * 4 + 3] + bcol[jc * 4 + 3];
            int cell = bx * 32 + tx * 2 + jc;
            size_t idx = (size_t)r * HDIM + cell;
            float cold = cbuf[idx];
            float hold = h_in[idx];
            float cn = cold * sigf(gf + 1.0f) + sigf(gi) * tanh_fast(gj);
            float hn = tanh_fast(cn) * sigf(go);
            if (act) {
                cbuf[idx]  = cn;
                h_out[idx] = hn;
            } else {
                h_out[idx] = hold;
            }
        }
    }
}

// ---------------------------------------------------------------------------
// Build h_combined = [h1, h2, dist, h1*h2]  (row length 3073, padded to 3088)
// ---------------------------------------------------------------------------
__global__ __launch_bounds__(256) void build_hc(const float* __restrict__ hfin,
                                                float* __restrict__ hc) {
    int b = blockIdx.x;
    int tid = threadIdx.x;
    __shared__ float red[256];
    float d = 0.0f;
    for (int k = tid; k < 1024; k += 256) {
        int dir = k >> 9, kk = k & 511;
        float h1 = hfin[(size_t)dir * ROWS * HDIM + (size_t)b * HDIM + kk];
        float h2 = hfin[(size_t)dir * ROWS * HDIM + (size_t)(BATCH + b) * HDIM + kk];
        size_t base = (size_t)b * HC_LD;
        hc[base + k]        = h1;
        hc[base + 1024 + k] = h2;
        hc[base + 2049 + k] = h1 * h2;
        float df = h1 - h2;
        d += df * df;
    }
    red[tid] = d;
    __syncthreads();
    for (int s = 128; s > 0; s >>= 1) {
        if (tid < s) red[tid] += red[tid + s];
        __syncthreads();
    }
    if (tid == 0) hc[(size_t)b * HC_LD + 2048] = red[0];
    if (tid < HC_LD - 3073) hc[(size_t)b * HC_LD + 3073 + tid] = 0.0f;
}

// ---------------------------------------------------------------------------
// e1 = relu(hc @ W1 + b1)   [1024 x 3073] @ [3073 x 512]
// 64x64 tile, BK=16, 256 threads, 4x4 per-thread
// ---------------------------------------------------------------------------
__global__ __launch_bounds__(256) void mlp1(const float* __restrict__ hc,
                                            const float* __restrict__ W1,
                                            const float* __restrict__ b1,
                                            float* __restrict__ e1) {
    const int bx = blockIdx.x, by = blockIdx.y, tid = threadIdx.x;
    __shared__ float As[16][72];
    __shared__ float Bs[16][68];
    const int tx = tid & 15, ty = tid >> 4;
    const int lr = tid >> 2, ks = (tid & 3) * 4;
    const int bkk = tid >> 4, bns = (tid & 15) * 4;

    float acc[4][4];
#pragma unroll
    for (int i = 0; i < 4; ++i)
#pragma unroll
        for (int j = 0; j < 4; ++j) acc[i][j] = 0.0f;

    for (int k0 = 0; k0 < HC_LD; k0 += 16) {
        float4 av = *(const float4*)&hc[(size_t)(by * 64 + lr) * HC_LD + k0 + ks];
        As[ks + 0][lr] = av.x; As[ks + 1][lr] = av.y;
        As[ks + 2][lr] = av.z; As[ks + 3][lr] = av.w;
        int kb = k0 + bkk;
        float4 bv = make_float4(0.f, 0.f, 0.f, 0.f);
        if (kb < 3073) bv = *(const float4*)&W1[(size_t)kb * MDIM + bx * 64 + bns];
        *(float4*)&Bs[bkk][bns] = bv;
        __syncthreads();
#pragma unroll
        for (int kk = 0; kk < 16; ++kk) {
            float a[4], b[4];
            *(float4*)a = *(const float4*)&As[kk][ty * 4];
            *(float4*)b = *(const float4*)&Bs[kk][tx * 4];
#pragma unroll
            for (int i = 0; i < 4; ++i)
#pragma unroll
                for (int j = 0; j < 4; ++j) acc[i][j] += a[i] * b[j];
        }
        __syncthreads();
    }
#pragma unroll
    for (int i = 0; i < 4; ++i) {
        int r = by * 64 + ty * 4 + i;
#pragma unroll
        for (int j = 0; j < 4; ++j) {
            int cidx = bx * 64 + tx * 4 + j;
            float v = acc[i][j] + b1[cidx];
            e1[(size_t)r * MDIM + cidx] = v > 0.0f ? v : 0.0f;
        }
    }
}

// ---------------------------------------------------------------------------
// preds = e1 @ W2 + b2   [1024 x 512] @ [512 x 2]
// ---------------------------------------------------------------------------
__global__ __launch_bounds__(64) void mlp2(const float* __restrict__ e1,
                                           const float* __restrict__ W2,
                                           const float* __restrict__ b2,
                                           float* __restrict__ out) {
    int b = blockIdx.x, tid = threadIdx.x;
    float p0 = 0.f, p1 = 0.f;
    for (int k = tid; k < 512; k += 64) {
        float e = e1[(size_t)b * MDIM + k];
        p0 += e * W2[2 * k];
        p1 += e * W2[2 * k + 1];
    }
    for (int off = 32; off > 0; off >>= 1) {
        p0 += __shfl_down(p0, off);
        p1 += __shfl_down(p1, off);
    }
    if (tid == 0) {
        out[2 * b]     = p0 + b2[0];
        out[2 * b + 1] = p1 + b2[1];
    }
}

// ---------------------------------------------------------------------------
extern "C" void kernel_launch(void* const* d_in, const int* in_sizes, int n_in,
                              void* d_out, int out_size, void* d_ws, size_t ws_size,
                              hipStream_t stream) {
    (void)in_sizes; (void)n_in; (void)out_size; (void)ws_size;
    const int*   in1 = (const int*)d_in[0];
    const int*   in2 = (const int*)d_in[1];
    const int*   sl1 = (const int*)d_in[2];
    const int*   sl2 = (const int*)d_in[3];
    const float* emb = (const float*)d_in[4];
    const float* kfw = (const float*)d_in[5];
    const float* bfw = (const float*)d_in[6];
    const float* kbw = (const float*)d_in[7];
    const float* bbw = (const float*)d_in[8];
    const float* W1  = (const float*)d_in[9];
    const float* b1  = (const float*)d_in[10];
    const float* W2  = (const float*)d_in[11];
    const float* b2  = (const float*)d_in[12];
    float* out = (float*)d_out;

    float* ws  = (float*)d_ws;
    float* Wr  = ws;                                // 2*1024*2048
    float* br  = Wr + (size_t)2 * 1024 * G4H;       // 2*2048
    float* cbf = br + 2 * G4H;                      // 2*2048*512
    float* hb0 = cbf + (size_t)2 * ROWS * HDIM;     // 2*2048*512
    float* hb1 = hb0 + (size_t)2 * ROWS * HDIM;     // 2*2048*512
    float* hc  = hb1 + (size_t)2 * ROWS * HDIM;     // 1024*3088
    float* e1  = hc + (size_t)BATCH * HC_LD;        // 1024*512

    // zero c and hb0 (initial state); everything else is fully overwritten
    hipMemsetAsync(cbf, 0, (size_t)2 * 2 * ROWS * HDIM * sizeof(float), stream);

    reorder_w<<<(2 * 1024 * G4H + 255) / 256, 256, 0, stream>>>(kfw, kbw, Wr);
    reorder_b<<<16, 256, 0, stream>>>(bfw, bbw, br);

    for (int t = 0; t < SEQL; ++t) {
        const float* hin = (t & 1) ? hb1 : hb0;
        float*       hout = (t & 1) ? hb0 : hb1;
        lstm_step<<<dim3(16, 16, 2), 256, 0, stream>>>(
            t, in1, in2, sl1, sl2, emb, Wr, br, hin, hout, cbf);
    }
    // SEQL even -> final h is in hb0

    build_hc<<<BATCH, 256, 0, stream>>>(hb0, hc);
    mlp1<<<dim3(MDIM / 64, BATCH / 64), 256, 0, stream>>>(hc, W1, b1, e1);
    mlp2<<<BATCH, 64, 0, stream>>>(e1, W2, b2, out);
}

// Round 2
// 3053.294 us; speedup vs baseline: 4.8400x; 4.8400x over previous
//
#include <hip/hip_runtime.h>
#include <hip/hip_bf16.h>
#include <cstddef>

// Problem constants
#define VOCAB 50000
#define D_EMB 512
#define HDIM  512
#define MDIM  512
#define BATCH 1024
#define SEQL  64
#define ROWS  2048          // 2 inputs * BATCH
#define KTOT  2048          // [x(512) | h_hi(512) | h_hi(512) | h_lo(512)]
#define HC_LD 3104          // 3073 padded to 97*32

typedef __attribute__((ext_vector_type(8))) short bf16x8;
typedef __attribute__((ext_vector_type(4))) float f32x4;

__device__ __forceinline__ float sigf(float x) {
    return 1.0f / (1.0f + __expf(-x));
}
__device__ __forceinline__ float tanh_fast(float x) {
    x = fminf(30.0f, fmaxf(-30.0f, x));
    float t = __expf(-2.0f * x);
    return (1.0f - t) / (1.0f + t);
}
__device__ __forceinline__ unsigned short f2bf(float x) {
    union { float f; unsigned u; } v; v.f = x;
    unsigned r = v.u + 0x7FFFu + ((v.u >> 16) & 1u);   // RNE
    return (unsigned short)(r >> 16);
}
__device__ __forceinline__ float bf2f(unsigned short h) {
    union { float f; unsigned u; } v; v.u = ((unsigned)h) << 16; return v.f;
}
__device__ __forceinline__ void glds16(const void* g, const void* lds) {
    __builtin_amdgcn_global_load_lds(
        (const __attribute__((address_space(1))) unsigned int*)g,
        (__attribute__((address_space(3))) unsigned int*)lds, 16, 0, 0);
}

// ---------------------------------------------------------------------------
// Convert embedding table fp32 -> bf16 (8 elems/thread)
// ---------------------------------------------------------------------------
__global__ __launch_bounds__(256) void conv_emb(const float* __restrict__ src,
                                                unsigned short* __restrict__ dst,
                                                int n8) {
    int i = blockIdx.x * 256 + threadIdx.x;
    if (i >= n8) return;
    const float4* s = (const float4*)src + (size_t)i * 2;
    float4 a = s[0], b = s[1];
    uint4 o;
    o.x = (unsigned)f2bf(a.x) | ((unsigned)f2bf(a.y) << 16);
    o.y = (unsigned)f2bf(a.z) | ((unsigned)f2bf(a.w) << 16);
    o.z = (unsigned)f2bf(b.x) | ((unsigned)f2bf(b.y) << 16);
    o.w = (unsigned)f2bf(b.z) | ((unsigned)f2bf(b.w) << 16);
    ((uint4*)dst)[i] = o;
}

// ---------------------------------------------------------------------------
// Pack weights: Wt[dir][col'][k]  (bf16), k-regions [Wx_hi;Wh_hi;Wh_lo;Wh_hi]
// col' = 64*(n>>4) + g*16 + (n&15)  (gate g of cell n)
// ---------------------------------------------------------------------------
__global__ __launch_bounds__(256) void pack_w(const float* __restrict__ kfw,
                                              const float* __restrict__ kbw,
                                              unsigned short* __restrict__ Wt) {
    unsigned idx = blockIdx.x * 256 + threadIdx.x;   // over 2*2048*2048
    int k    = idx & 2047;
    int colp = (idx >> 11) & 2047;
    int d    = idx >> 22;
    int cg = colp >> 6, g = (colp >> 4) & 3, ci = colp & 15;
    int n = cg * 16 + ci;
    int reg = k >> 9, ks = k & 511;
    const float* K = d ? kbw : kfw;
    int srow = (reg == 0) ? ks : (512 + ks);
    float v = K[(size_t)srow * 2048 + g * 512 + n];
    unsigned short hi = f2bf(v);
    Wt[idx] = (reg == 2) ? f2bf(v - bf2f(hi)) : hi;
}

// ---------------------------------------------------------------------------
// One LSTM timestep (both dirs, 2048 rows). 128x128 tile, BK=64, 4 waves,
// MFMA 16x16x32 bf16, global_load_lds staging w/ XOR-swizzled sources.
// ---------------------------------------------------------------------------
__global__ __launch_bounds__(256) void lstm_step(
    int t,
    const int* __restrict__ in1, const int* __restrict__ in2,
    const int* __restrict__ sl1, const int* __restrict__ sl2,
    const unsigned short* __restrict__ embB,   // [VOCAB][512] bf16
    const unsigned short* __restrict__ Wt,     // [2][2048 col'][2048 k] bf16
    const float* __restrict__ bfw, const float* __restrict__ bbw,
    const unsigned short* __restrict__ hinHi, const unsigned short* __restrict__ hinLo,
    unsigned short* __restrict__ houtHi, unsigned short* __restrict__ houtLo,
    float* __restrict__ cbuf)                  // [2][2048][512] fp32
{
    const int dir = blockIdx.z;
    const int bx  = blockIdx.x;    // col tile (0..15)
    const int by  = blockIdx.y;    // row tile (0..15)
    const int tid = threadIdx.x;
    const int l = tid & 63, w = tid >> 6;

    __shared__ short Atile[1024 * 8];   // 16 KB: 128 rows x 8 slots x 8 bf16
    __shared__ short Btile[1024 * 8];   // 16 KB: 128 cols x 8 slots x 8 bf16
    __shared__ int toks[128];
    __shared__ int slens[128];

    if (tid < 128) {
        int r = by * 128 + tid;
        int b = r & (BATCH - 1);
        const int* inp = (r < BATCH) ? in1 : in2;
        int s = (r < BATCH) ? sl1[b] : sl2[b];
        int tt = t;
        if (dir == 1) tt = (t < s) ? (s - 1 - t) : t;
        toks[tid]  = inp[b * SEQL + tt];
        slens[tid] = s;
    }
    __syncthreads();

    // per-lane staging constants: slot swizzle kg = (l&7)^((l>>3)&7)
    const int kg8 = (((l & 7) ^ ((l >> 3) & 7))) * 8;   // shorts within row
    int aoffX[4]; int hoff[4]; size_t boff[4];
#pragma unroll
    for (int r = 0; r < 4; ++r) {
        int row = r * 32 + w * 8 + (l >> 3);
        aoffX[r] = toks[row] * 512 + kg8;
        hoff[r]  = ((dir * ROWS + by * 128 + row) << 9) + kg8;
        boff[r]  = ((size_t)(dir * 2048 + bx * 128 + row) << 11) + kg8;
    }

    f32x4 acc[4][4];
#pragma unroll
    for (int i = 0; i < 4; ++i)
#pragma unroll
        for (int j = 0; j < 4; ++j) acc[i][j] = (f32x4){0.f, 0.f, 0.f, 0.f};

    const int wr = w >> 1, wc = w & 1;

    for (int kt = 0; kt < 32; ++kt) {
        const int r0 = kt >> 3;               // A region 0..3
        const int klocal = (kt & 7) << 6;     // shorts within region row
        // ---- A staging (4 x global_load_lds dwordx4 per thread)
#pragma unroll
        for (int r = 0; r < 4; ++r) {
            const unsigned short* src;
            if (r0 == 0)      src = embB  + aoffX[r] + klocal;
            else if (r0 == 3) src = hinLo + hoff[r] + klocal;
            else              src = hinHi + hoff[r] + klocal;
            glds16(src, &Atile[(r * 256 + w * 64) * 8]);
        }
        // ---- B staging
#pragma unroll
        for (int r = 0; r < 4; ++r) {
            glds16(Wt + boff[r] + kt * 64, &Btile[(r * 256 + w * 64) * 8]);
        }
        __syncthreads();   // drains vmcnt -> LDS tiles ready

#pragma unroll
        for (int kk = 0; kk < 2; ++kk) {
            bf16x8 af[4], bv[4];
            const int slot = (l >> 4) + kk * 4;
#pragma unroll
            for (int fm = 0; fm < 4; ++fm) {
                int row = wr * 64 + fm * 16 + (l & 15);
                af[fm] = *(const bf16x8*)&Atile[(row * 8 + (slot ^ (row & 7))) * 8];
            }
#pragma unroll
            for (int fn = 0; fn < 4; ++fn) {
                int col = wc * 64 + fn * 16 + (l & 15);
                bv[fn] = *(const bf16x8*)&Btile[(col * 8 + (slot ^ (col & 7))) * 8];
            }
#pragma unroll
            for (int fm = 0; fm < 4; ++fm)
#pragma unroll
                for (int fn = 0; fn < 4; ++fn)
                    acc[fm][fn] = __builtin_amdgcn_mfma_f32_16x16x32_bf16(
                        af[fm], bv[fn], acc[fm][fn], 0, 0, 0);
        }
        __syncthreads();
    }

    // ---- fused LSTM epilogue: lane owns cell = bx*32 + wc*16 + (l&15),
    //      gate g = fragment fn; rows = wr*64 + fm*16 + (l>>4)*4 + reg
    const float* bias = dir ? bbw : bfw;
    const int cell = bx * 32 + wc * 16 + (l & 15);
    float bg[4];
#pragma unroll
    for (int g = 0; g < 4; ++g) bg[g] = bias[g * 512 + cell];

#pragma unroll
    for (int fm = 0; fm < 4; ++fm) {
#pragma unroll
        for (int reg = 0; reg < 4; ++reg) {
            int rl = wr * 64 + fm * 16 + (l >> 4) * 4 + reg;
            bool act = (t < slens[rl]);
            size_t idx = ((size_t)(dir * ROWS + by * 128 + rl) << 9) + cell;
            float gi = acc[fm][0][reg] + bg[0];
            float gj = acc[fm][1][reg] + bg[1];
            float gf = acc[fm][2][reg] + bg[2];
            float go = acc[fm][3][reg] + bg[3];
            if (act) {
                float cold = cbuf[idx];
                float cn = cold * sigf(gf + 1.0f) + sigf(gi) * tanh_fast(gj);
                float hn = tanh_fast(cn) * sigf(go);
                cbuf[idx] = cn;
                unsigned short hhi = f2bf(hn);
                houtHi[idx] = hhi;
                houtLo[idx] = f2bf(hn - bf2f(hhi));
            } else {
                houtHi[idx] = hinHi[idx];
                houtLo[idx] = hinLo[idx];
            }
        }
    }
}

// ---------------------------------------------------------------------------
// Build h_combined = [h1, h2, dist, h1*h2]  (row length 3073, padded)
// ---------------------------------------------------------------------------
__global__ __launch_bounds__(256) void build_hc(const unsigned short* __restrict__ hHi,
                                                const unsigned short* __restrict__ hLo,
                                                float* __restrict__ hc) {
    int b = blockIdx.x;
    int tid = threadIdx.x;
    __shared__ float red[256];
    float d = 0.0f;
    for (int k = tid; k < 1024; k += 256) {
        int dir = k >> 9, kk = k & 511;
        size_t i1 = ((size_t)(dir * ROWS + b) << 9) + kk;
        size_t i2 = ((size_t)(dir * ROWS + BATCH + b) << 9) + kk;
        float h1 = bf2f(hHi[i1]) + bf2f(hLo[i1]);
        float h2 = bf2f(hHi[i2]) + bf2f(hLo[i2]);
        size_t base = (size_t)b * HC_LD;
        hc[base + k]        = h1;
        hc[base + 1024 + k] = h2;
        hc[base + 2049 + k] = h1 * h2;
        float df = h1 - h2;
        d += df * df;
    }
    red[tid] = d;
    __syncthreads();
    for (int s = 128; s > 0; s >>= 1) {
        if (tid < s) red[tid] += red[tid + s];
        __syncthreads();
    }
    if (tid == 0) hc[(size_t)b * HC_LD + 2048] = red[0];
    if (tid < HC_LD - 3073) hc[(size_t)b * HC_LD + 3073 + tid] = 0.0f;
}

// ---------------------------------------------------------------------------
// e1 = relu(hc @ W1 + b1)   [1024 x 3073] @ [3073 x 512]  fp32
// 32x64 tile, BK=32, 256 threads, 2x4 per-thread -> 256 blocks
// ---------------------------------------------------------------------------
__global__ __launch_bounds__(256) void mlp1(const float* __restrict__ hc,
                                            const float* __restrict__ W1,
                                            const float* __restrict__ b1,
                                            float* __restrict__ e1) {
    const int bx = blockIdx.x, by = blockIdx.y, tid = threadIdx.x;
    __shared__ float As[32][33];
    __shared__ float Bs[32][68];
    const int tx = tid & 15, ty = tid >> 4;
    const int ar = tid >> 3, ak = (tid & 7) * 4;
    const int bk = tid >> 3, bc = (tid & 7) * 8;

    float acc[2][4];
#pragma unroll
    for (int i = 0; i < 2; ++i)
#pragma unroll
        for (int j = 0; j < 4; ++j) acc[i][j] = 0.0f;

    for (int k0 = 0; k0 < HC_LD; k0 += 32) {
        float4 av = *(const float4*)&hc[(size_t)(by * 32 + ar) * HC_LD + k0 + ak];
        As[ar][ak + 0] = av.x; As[ar][ak + 1] = av.y;
        As[ar][ak + 2] = av.z; As[ar][ak + 3] = av.w;
        int kb = k0 + bk;
        float4 b0 = make_float4(0.f, 0.f, 0.f, 0.f), b1v = b0;
        if (kb < 3073) {
            const float* wsrc = &W1[(size_t)kb * MDIM + bx * 64 + bc];
            b0 = *(const float4*)wsrc;
            b1v = *(const float4*)(wsrc + 4);
        }
        *(float4*)&Bs[bk][bc]     = b0;
        *(float4*)&Bs[bk][bc + 4] = b1v;
        __syncthreads();
#pragma unroll
        for (int kk = 0; kk < 32; ++kk) {
            float a0 = As[ty * 2][kk], a1 = As[ty * 2 + 1][kk];
            float4 bvv = *(const float4*)&Bs[kk][tx * 4];
            acc[0][0] += a0 * bvv.x; acc[0][1] += a0 * bvv.y;
            acc[0][2] += a0 * bvv.z; acc[0][3] += a0 * bvv.w;
            acc[1][0] += a1 * bvv.x; acc[1][1] += a1 * bvv.y;
            acc[1][2] += a1 * bvv.z; acc[1][3] += a1 * bvv.w;
        }
        __syncthreads();
    }
#pragma unroll
    for (int i = 0; i < 2; ++i) {
        int r = by * 32 + ty * 2 + i;
#pragma unroll
        for (int j = 0; j < 4; ++j) {
            int c = bx * 64 + tx * 4 + j;
            float v = acc[i][j] + b1[c];
            e1[(size_t)r * MDIM + c] = v > 0.0f ? v : 0.0f;
        }
    }
}

// ---------------------------------------------------------------------------
// preds = e1 @ W2 + b2   [1024 x 512] @ [512 x 2]
// ---------------------------------------------------------------------------
__global__ __launch_bounds__(64) void mlp2(const float* __restrict__ e1,
                                           const float* __restrict__ W2,
                                           const float* __restrict__ b2,
                                           float* __restrict__ out) {
    int b = blockIdx.x, tid = threadIdx.x;
    float p0 = 0.f, p1 = 0.f;
    for (int k = tid; k < 512; k += 64) {
        float e = e1[(size_t)b * MDIM + k];
        p0 += e * W2[2 * k];
        p1 += e * W2[2 * k + 1];
    }
    for (int off = 32; off > 0; off >>= 1) {
        p0 += __shfl_down(p0, off);
        p1 += __shfl_down(p1, off);
    }
    if (tid == 0) {
        out[2 * b]     = p0 + b2[0];
        out[2 * b + 1] = p1 + b2[1];
    }
}

// ---------------------------------------------------------------------------
extern "C" void kernel_launch(void* const* d_in, const int* in_sizes, int n_in,
                              void* d_out, int out_size, void* d_ws, size_t ws_size,
                              hipStream_t stream) {
    (void)in_sizes; (void)n_in; (void)out_size; (void)ws_size;
    const int*   in1 = (const int*)d_in[0];
    const int*   in2 = (const int*)d_in[1];
    const int*   sl1 = (const int*)d_in[2];
    const int*   sl2 = (const int*)d_in[3];
    const float* emb = (const float*)d_in[4];
    const float* kfw = (const float*)d_in[5];
    const float* bfw = (const float*)d_in[6];
    const float* kbw = (const float*)d_in[7];
    const float* bbw = (const float*)d_in[8];
    const float* W1  = (const float*)d_in[9];
    const float* b1  = (const float*)d_in[10];
    const float* W2  = (const float*)d_in[11];
    const float* b2  = (const float*)d_in[12];
    float* out = (float*)d_out;

    char* base = (char*)d_ws;
    unsigned short* embB = (unsigned short*)base;                     // 51,200,000 B
    unsigned short* Wt   = (unsigned short*)(base + 51200000);        // 16,777,216 B
    float*          cbuf = (float*)(base + 67977216);                 //  8,388,608 B
    unsigned short* h0Hi = (unsigned short*)(base + 76365824);        //  4,194,304 B
    unsigned short* h0Lo = (unsigned short*)(base + 80560128);        //  4,194,304 B
    unsigned short* h1Hi = (unsigned short*)(base + 84754432);        //  4,194,304 B
    unsigned short* h1Lo = (unsigned short*)(base + 88948736);        //  4,194,304 B
    float*          hc   = (float*)(base + 93143040);                 // 12,713,984 B
    float*          e1   = (float*)(base + 105857024);                //  2,097,152 B

    // zero c and h0 (initial state)
    hipMemsetAsync(cbuf, 0, 8388608, stream);
    hipMemsetAsync(h0Hi, 0, 2 * 4194304, stream);   // h0Hi + h0Lo adjacent

    conv_emb<<<(VOCAB * D_EMB / 8 + 255) / 256, 256, 0, stream>>>(emb, embB, VOCAB * D_EMB / 8);
    pack_w<<<(2 * 2048 * 2048) / 256, 256, 0, stream>>>(kfw, kbw, Wt);

    for (int t = 0; t < SEQL; ++t) {
        const unsigned short* hiH = (t & 1) ? h1Hi : h0Hi;
        const unsigned short* hiL = (t & 1) ? h1Lo : h0Lo;
        unsigned short* hoH = (t & 1) ? h0Hi : h1Hi;
        unsigned short* hoL = (t & 1) ? h0Lo : h1Lo;
        lstm_step<<<dim3(16, 16, 2), 256, 0, stream>>>(
            t, in1, in2, sl1, sl2, embB, Wt, bfw, bbw,
            hiH, hiL, hoH, hoL, cbuf);
    }
    // SEQL=64 even -> final h is in (h0Hi, h0Lo)

    build_hc<<<BATCH, 256, 0, stream>>>(h0Hi, h0Lo, hc);
    mlp1<<<dim3(MDIM / 64, BATCH / 32), 256, 0, stream>>>(hc, W1, b1, e1);
    mlp2<<<BATCH, 64, 0, stream>>>(e1, W2, b2, out);
}

// Round 3
// 2081.272 us; speedup vs baseline: 7.1005x; 1.4670x over previous
//
#include <hip/hip_runtime.h>
#include <hip/hip_bf16.h>
#include <cstddef>

// Problem constants
#define VOCAB 50000
#define D_EMB 512
#define HDIM  512
#define MDIM  512
#define BATCH 1024
#define SEQL  64
#define ROWS  2048          // 2 inputs * BATCH
#define KTOT  1024          // [x(512) | h(512)]
#define HC_K  3136          // 3073 padded to 49*64

typedef _Float16 f16;
typedef __attribute__((ext_vector_type(8))) _Float16 f16x8;
typedef __attribute__((ext_vector_type(4))) float f32x4;

__device__ __forceinline__ float sigf(float x) {
    return 1.0f / (1.0f + __expf(-x));
}
__device__ __forceinline__ float tanh_fast(float x) {
    x = fminf(30.0f, fmaxf(-30.0f, x));
    float t = __expf(-2.0f * x);
    return (1.0f - t) / (1.0f + t);
}
__device__ __forceinline__ void glds16(const void* g, const void* lds) {
    __builtin_amdgcn_global_load_lds(
        (const __attribute__((address_space(1))) unsigned int*)g,
        (__attribute__((address_space(3))) unsigned int*)lds, 16, 0, 0);
}

// ---------------------------------------------------------------------------
// Convert embedding table fp32 -> fp16 (8 elems/thread)
// ---------------------------------------------------------------------------
__global__ __launch_bounds__(256) void conv_emb(const float* __restrict__ src,
                                                f16* __restrict__ dst, int n8) {
    int i = blockIdx.x * 256 + threadIdx.x;
    if (i >= n8) return;
    const float4* s = (const float4*)src + (size_t)i * 2;
    float4 a = s[0], b = s[1];
    f16x8 o = {(f16)a.x, (f16)a.y, (f16)a.z, (f16)a.w,
               (f16)b.x, (f16)b.y, (f16)b.z, (f16)b.w};
    *(f16x8*)&dst[(size_t)i * 8] = o;
}

// ---------------------------------------------------------------------------
// Pack LSTM weights: Wt[dir][col'][k]  (fp16), k = [Wx(512);Wh(512)]
// col' = 64*(n>>4) + g*16 + (n&15)  (gate g of cell n)
// ---------------------------------------------------------------------------
__global__ __launch_bounds__(256) void pack_w(const float* __restrict__ kfw,
                                              const float* __restrict__ kbw,
                                              f16* __restrict__ Wt) {
    unsigned idx = blockIdx.x * 256 + threadIdx.x;   // over 2*2048*1024
    int k    = idx & 1023;
    int colp = (idx >> 10) & 2047;
    int d    = idx >> 21;
    int cg = colp >> 6, g = (colp >> 4) & 3, ci = colp & 15;
    int n = cg * 16 + ci;
    const float* K = d ? kbw : kfw;
    Wt[idx] = (f16)K[(size_t)k * 2048 + g * 512 + n];
}

// ---------------------------------------------------------------------------
// Pack W1: W1t[col][k] fp16, k padded 3073 -> 3136 with zeros
// ---------------------------------------------------------------------------
__global__ __launch_bounds__(256) void pack_w1(const float* __restrict__ W1,
                                               f16* __restrict__ W1t) {
    int idx = blockIdx.x * 256 + threadIdx.x;        // over 512*3136
    if (idx >= 512 * HC_K) return;
    int k = idx % HC_K, c = idx / HC_K;
    W1t[idx] = (k < 3073) ? (f16)W1[(size_t)k * MDIM + c] : (f16)0.0f;
}

// ---------------------------------------------------------------------------
// One LSTM timestep (both dirs, 2048 rows). 128x128 tile, BK=64, 4 waves,
// MFMA 16x16x32 f16, 2-phase double-buffered global_load_lds staging,
// XOR-swizzled LDS (swizzle applied on source addr + read addr).
// ---------------------------------------------------------------------------
__global__ __launch_bounds__(256, 2) void lstm_step(
    int t,
    const int* __restrict__ in1, const int* __restrict__ in2,
    const int* __restrict__ sl1, const int* __restrict__ sl2,
    const f16* __restrict__ embH,   // [VOCAB][512]
    const f16* __restrict__ Wt,     // [2][2048 col'][1024 k]
    const float* __restrict__ bfw, const float* __restrict__ bbw,
    const f16* __restrict__ hin,    // [2][2048][512]
    f16* __restrict__ hout,
    float* __restrict__ cbuf)       // [2][2048][512] fp32
{
    const int dir = blockIdx.z;
    const int bx  = blockIdx.x;    // col tile (0..15)
    const int by  = blockIdx.y;    // row tile (0..15)
    const int tid = threadIdx.x;
    const int l = tid & 63, w = tid >> 6;

    __shared__ f16 Atile[2][128 * 64];   // 16 KB each
    __shared__ f16 Btile[2][128 * 64];
    __shared__ int toks[128];
    __shared__ int slens[128];

    if (tid < 128) {
        int r = by * 128 + tid;
        int b = r & (BATCH - 1);
        const int* inp = (r < BATCH) ? in1 : in2;
        int s = (r < BATCH) ? sl1[b] : sl2[b];
        int tt = t;
        if (dir == 1) tt = (t < s) ? (s - 1 - t) : t;
        toks[tid]  = inp[b * SEQL + tt];
        slens[tid] = s;
    }
    __syncthreads();

    // staging: thread covers rows {r*32 + w*8 + (l>>3)}, 16B k-chunk kg
    const int kg8 = (((l & 7) ^ ((l >> 3) & 7))) * 8;   // swizzled k offset (f16)
    int aoffX[4]; int hoff[4]; size_t boff[4]; int dst[4];
#pragma unroll
    for (int r = 0; r < 4; ++r) {
        int row = r * 32 + w * 8 + (l >> 3);
        aoffX[r] = toks[row] * 512 + kg8;
        hoff[r]  = ((dir * ROWS + by * 128 + row) << 9) + kg8;
        boff[r]  = ((size_t)(dir * 2048 + bx * 128 + row) << 10) + kg8;
        dst[r]   = (r * 32 + w * 8) * 64;    // wave-uniform LDS base (f16 units)
    }

    f32x4 acc[4][4];
#pragma unroll
    for (int i = 0; i < 4; ++i)
#pragma unroll
        for (int j = 0; j < 4; ++j) acc[i][j] = (f32x4){0.f, 0.f, 0.f, 0.f};

    const int wr = w >> 1, wc = w & 1;

    // prologue: stage k-tile 0 into buf 0
#pragma unroll
    for (int r = 0; r < 4; ++r) {
        glds16(embH + aoffX[r], &Atile[0][dst[r]]);
        glds16(Wt + boff[r], &Btile[0][dst[r]]);
    }
    __syncthreads();

    int cur = 0;
    for (int kt = 0; kt < 16; ++kt) {
        // ---- prefetch next k-tile into the other buffer
        if (kt < 15) {
            const int kn = kt + 1;
#pragma unroll
            for (int r = 0; r < 4; ++r) {
                const f16* asrc = (kn < 8) ? (embH + aoffX[r] + kn * 64)
                                           : (hin + hoff[r] + (kn - 8) * 64);
                glds16(asrc, &Atile[cur ^ 1][dst[r]]);
                glds16(Wt + boff[r] + kn * 64, &Btile[cur ^ 1][dst[r]]);
            }
        }
        // ---- compute current tile
#pragma unroll
        for (int kk = 0; kk < 2; ++kk) {
            f16x8 af[4], bv[4];
            const int slot = (l >> 4) + kk * 4;
#pragma unroll
            for (int fm = 0; fm < 4; ++fm) {
                int row = wr * 64 + fm * 16 + (l & 15);
                af[fm] = *(const f16x8*)&Atile[cur][row * 64 + (slot ^ (row & 7)) * 8];
            }
#pragma unroll
            for (int fn = 0; fn < 4; ++fn) {
                int col = wc * 64 + fn * 16 + (l & 15);
                bv[fn] = *(const f16x8*)&Btile[cur][col * 64 + (slot ^ (col & 7)) * 8];
            }
#pragma unroll
            for (int fm = 0; fm < 4; ++fm)
#pragma unroll
                for (int fn = 0; fn < 4; ++fn)
                    acc[fm][fn] = __builtin_amdgcn_mfma_f32_16x16x32_f16(
                        af[fm], bv[fn], acc[fm][fn], 0, 0, 0);
        }
        __syncthreads();   // drains prefetch vmcnt + guards buffer swap
        cur ^= 1;
    }

    // ---- fused LSTM epilogue: lane owns cell = bx*32 + wc*16 + (l&15),
    //      gate g = fragment fn; rows = wr*64 + fm*16 + (l>>4)*4 + reg
    const float* bias = dir ? bbw : bfw;
    const int cell = bx * 32 + wc * 16 + (l & 15);
    float bg[4];
#pragma unroll
    for (int g = 0; g < 4; ++g) bg[g] = bias[g * 512 + cell];

#pragma unroll
    for (int fm = 0; fm < 4; ++fm) {
#pragma unroll
        for (int reg = 0; reg < 4; ++reg) {
            int rl = wr * 64 + fm * 16 + (l >> 4) * 4 + reg;
            bool act = (t < slens[rl]);
            size_t idx = ((size_t)(dir * ROWS + by * 128 + rl) << 9) + cell;
            float gi = acc[fm][0][reg] + bg[0];
            float gj = acc[fm][1][reg] + bg[1];
            float gf = acc[fm][2][reg] + bg[2];
            float go = acc[fm][3][reg] + bg[3];
            if (act) {
                float cold = cbuf[idx];
                float cn = cold * sigf(gf + 1.0f) + sigf(gi) * tanh_fast(gj);
                float hn = tanh_fast(cn) * sigf(go);
                cbuf[idx] = cn;
                hout[idx] = (f16)hn;
            } else {
                hout[idx] = hin[idx];
            }
        }
    }
}

// ---------------------------------------------------------------------------
// Build h_combined fp16 [1024][3136] = [h1, h2, dist, h1*h2, 0-pad]
// ---------------------------------------------------------------------------
__global__ __launch_bounds__(256) void build_hc(const f16* __restrict__ hfin,
                                                f16* __restrict__ hc) {
    int b = blockIdx.x;
    int tid = threadIdx.x;
    __shared__ float red[256];
    float d = 0.0f;
    size_t base = (size_t)b * HC_K;
    for (int k = tid; k < 1024; k += 256) {
        int dir = k >> 9, kk = k & 511;
        size_t i1 = ((size_t)(dir * ROWS + b) << 9) + kk;
        size_t i2 = ((size_t)(dir * ROWS + BATCH + b) << 9) + kk;
        float h1 = (float)hfin[i1];
        float h2 = (float)hfin[i2];
        hc[base + k]        = (f16)h1;
        hc[base + 1024 + k] = (f16)h2;
        hc[base + 2049 + k] = (f16)(h1 * h2);
        float df = h1 - h2;
        d += df * df;
    }
    red[tid] = d;
    __syncthreads();
    for (int s = 128; s > 0; s >>= 1) {
        if (tid < s) red[tid] += red[tid + s];
        __syncthreads();
    }
    if (tid == 0) hc[base + 2048] = (f16)red[0];
    if (tid < HC_K - 3073) hc[base + 3073 + tid] = (f16)0.0f;
}

// ---------------------------------------------------------------------------
// e1 = relu(hc @ W1 + b1)   fp16 MFMA, 64x64 tile, BK=64, 4 waves (2x2),
// 2-phase double-buffered staging. K = 3136 (49 tiles).
// ---------------------------------------------------------------------------
__global__ __launch_bounds__(256) void mlp1(const f16* __restrict__ hc,
                                            const f16* __restrict__ W1t,
                                            const float* __restrict__ b1,
                                            float* __restrict__ e1) {
    const int bx = blockIdx.x, by = blockIdx.y, tid = threadIdx.x;
    const int l = tid & 63, w = tid >> 6;
    __shared__ f16 Atile[2][64 * 64];   // 8 KB each
    __shared__ f16 Btile[2][64 * 64];

    const int kg8 = (((l & 7) ^ ((l >> 3) & 7))) * 8;
    size_t aoff[2], boff[2]; int dst[2];
#pragma unroll
    for (int g = 0; g < 2; ++g) {
        int row = g * 32 + w * 8 + (l >> 3);
        aoff[g] = (size_t)(by * 64 + row) * HC_K + kg8;
        boff[g] = (size_t)(bx * 64 + row) * HC_K + kg8;
        dst[g]  = (g * 32 + w * 8) * 64;
    }

    f32x4 acc[2][2];
#pragma unroll
    for (int i = 0; i < 2; ++i)
#pragma unroll
        for (int j = 0; j < 2; ++j) acc[i][j] = (f32x4){0.f, 0.f, 0.f, 0.f};

    const int wr = w >> 1, wc = w & 1;

#pragma unroll
    for (int g = 0; g < 2; ++g) {
        glds16(hc + aoff[g], &Atile[0][dst[g]]);
        glds16(W1t + boff[g], &Btile[0][dst[g]]);
    }
    __syncthreads();

    int cur = 0;
    for (int kt = 0; kt < HC_K / 64; ++kt) {
        if (kt < HC_K / 64 - 1) {
            const int kn = (kt + 1) * 64;
#pragma unroll
            for (int g = 0; g < 2; ++g) {
                glds16(hc + aoff[g] + kn, &Atile[cur ^ 1][dst[g]]);
                glds16(W1t + boff[g] + kn, &Btile[cur ^ 1][dst[g]]);
            }
        }
#pragma unroll
        for (int kk = 0; kk < 2; ++kk) {
            f16x8 af[2], bv[2];
            const int slot = (l >> 4) + kk * 4;
#pragma unroll
            for (int fm = 0; fm < 2; ++fm) {
                int row = wr * 32 + fm * 16 + (l & 15);
                af[fm] = *(const f16x8*)&Atile[cur][row * 64 + (slot ^ (row & 7)) * 8];
            }
#pragma unroll
            for (int fn = 0; fn < 2; ++fn) {
                int col = wc * 32 + fn * 16 + (l & 15);
                bv[fn] = *(const f16x8*)&Btile[cur][col * 64 + (slot ^ (col & 7)) * 8];
            }
#pragma unroll
            for (int fm = 0; fm < 2; ++fm)
#pragma unroll
                for (int fn = 0; fn < 2; ++fn)
                    acc[fm][fn] = __builtin_amdgcn_mfma_f32_16x16x32_f16(
                        af[fm], bv[fn], acc[fm][fn], 0, 0, 0);
        }
        __syncthreads();
        cur ^= 1;
    }

#pragma unroll
    for (int fm = 0; fm < 2; ++fm) {
#pragma unroll
        for (int fn = 0; fn < 2; ++fn) {
#pragma unroll
            for (int reg = 0; reg < 4; ++reg) {
                int r = by * 64 + wr * 32 + fm * 16 + (l >> 4) * 4 + reg;
                int c = bx * 64 + wc * 32 + fn * 16 + (l & 15);
                float v = acc[fm][fn][reg] + b1[c];
                e1[(size_t)r * MDIM + c] = v > 0.0f ? v : 0.0f;
            }
        }
    }
}

// ---------------------------------------------------------------------------
// preds = e1 @ W2 + b2   [1024 x 512] @ [512 x 2]
// ---------------------------------------------------------------------------
__global__ __launch_bounds__(64) void mlp2(const float* __restrict__ e1,
                                           const float* __restrict__ W2,
                                           const float* __restrict__ b2,
                                           float* __restrict__ out) {
    int b = blockIdx.x, tid = threadIdx.x;
    float p0 = 0.f, p1 = 0.f;
    for (int k = tid; k < 512; k += 64) {
        float e = e1[(size_t)b * MDIM + k];
        p0 += e * W2[2 * k];
        p1 += e * W2[2 * k + 1];
    }
    for (int off = 32; off > 0; off >>= 1) {
        p0 += __shfl_down(p0, off);
        p1 += __shfl_down(p1, off);
    }
    if (tid == 0) {
        out[2 * b]     = p0 + b2[0];
        out[2 * b + 1] = p1 + b2[1];
    }
}

// ---------------------------------------------------------------------------
extern "C" void kernel_launch(void* const* d_in, const int* in_sizes, int n_in,
                              void* d_out, int out_size, void* d_ws, size_t ws_size,
                              hipStream_t stream) {
    (void)in_sizes; (void)n_in; (void)out_size; (void)ws_size;
    const int*   in1 = (const int*)d_in[0];
    const int*   in2 = (const int*)d_in[1];
    const int*   sl1 = (const int*)d_in[2];
    const int*   sl2 = (const int*)d_in[3];
    const float* emb = (const float*)d_in[4];
    const float* kfw = (const float*)d_in[5];
    const float* bfw = (const float*)d_in[6];
    const float* kbw = (const float*)d_in[7];
    const float* bbw = (const float*)d_in[8];
    const float* W1  = (const float*)d_in[9];
    const float* b1  = (const float*)d_in[10];
    const float* W2  = (const float*)d_in[11];
    const float* b2  = (const float*)d_in[12];
    float* out = (float*)d_out;

    char* base = (char*)d_ws;
    f16*   embH = (f16*)base;                      // 51,200,000 B
    f16*   Wt   = (f16*)(base + 51200000);         //  8,388,608 B
    f16*   W1t  = (f16*)(base + 59588608);         //  3,211,264 B
    float* cbuf = (float*)(base + 62799872);       //  8,388,608 B
    f16*   h0   = (f16*)(base + 71188480);         //  4,194,304 B
    f16*   h1   = (f16*)(base + 75382784);         //  4,194,304 B
    f16*   hc   = (f16*)(base + 79577088);         //  6,422,528 B
    float* e1   = (float*)(base + 85999616);       //  2,097,152 B

    // zero c and h0 (initial state)
    hipMemsetAsync(cbuf, 0, 8388608, stream);
    hipMemsetAsync(h0, 0, 4194304, stream);

    conv_emb<<<(VOCAB * D_EMB / 8 + 255) / 256, 256, 0, stream>>>(emb, embH, VOCAB * D_EMB / 8);
    pack_w<<<(2 * 2048 * KTOT) / 256, 256, 0, stream>>>(kfw, kbw, Wt);
    pack_w1<<<(512 * HC_K + 255) / 256, 256, 0, stream>>>(W1, W1t);

    for (int t = 0; t < SEQL; ++t) {
        const f16* hi = (t & 1) ? h1 : h0;
        f16*       ho = (t & 1) ? h0 : h1;
        lstm_step<<<dim3(16, 16, 2), 256, 0, stream>>>(
            t, in1, in2, sl1, sl2, embH, Wt, bfw, bbw, hi, ho, cbuf);
    }
    // SEQL=64 even -> final h is in h0

    build_hc<<<BATCH, 256, 0, stream>>>(h0, hc);
    mlp1<<<dim3(MDIM / 64, BATCH / 64), 256, 0, stream>>>(hc, W1t, b1, e1);
    mlp2<<<BATCH, 64, 0, stream>>>(e1, W2, b2, out);
}

// Round 4
// 1985.374 us; speedup vs baseline: 7.4435x; 1.0483x over previous
//
#include <hip/hip_runtime.h>
#include <hip/hip_bf16.h>
#include <cstddef>

// Problem constants
#define VOCAB 50000
#define D_EMB 512
#define HDIM  512
#define MDIM  512
#define BATCH 1024
#define SEQL  64
#define ROWS  2048          // 2 inputs * BATCH
#define KTOT  1024          // [x(512) | h(512)]
#define HC_K  3136          // 3073 padded to 49*64

typedef _Float16 f16;
typedef __attribute__((ext_vector_type(8))) _Float16 f16x8;
typedef __attribute__((ext_vector_type(4))) float f32x4;

__device__ __forceinline__ float sigf(float x) {
    return 1.0f / (1.0f + __expf(-x));
}
__device__ __forceinline__ float tanh_fast(float x) {
    x = fminf(30.0f, fmaxf(-30.0f, x));
    float t = __expf(-2.0f * x);
    return (1.0f - t) / (1.0f + t);
}
__device__ __forceinline__ void glds16(const void* g, const void* lds) {
    __builtin_amdgcn_global_load_lds(
        (const __attribute__((address_space(1))) unsigned int*)g,
        (__attribute__((address_space(3))) unsigned int*)lds, 16, 0, 0);
}

// ---------------------------------------------------------------------------
// Convert embedding table fp32 -> fp16 (8 elems/thread)
// ---------------------------------------------------------------------------
__global__ __launch_bounds__(256) void conv_emb(const float* __restrict__ src,
                                                f16* __restrict__ dst, int n8) {
    int i = blockIdx.x * 256 + threadIdx.x;
    if (i >= n8) return;
    const float4* s = (const float4*)src + (size_t)i * 2;
    float4 a = s[0], b = s[1];
    f16x8 o = {(f16)a.x, (f16)a.y, (f16)a.z, (f16)a.w,
               (f16)b.x, (f16)b.y, (f16)b.z, (f16)b.w};
    *(f16x8*)&dst[(size_t)i * 8] = o;
}

// ---------------------------------------------------------------------------
// Pack LSTM weights: Wt[dir][col'][k]  (fp16), k = [Wx(512);Wh(512)]
// col' = 64*(n>>4) + g*16 + (n&15)  (gate g of cell n)
// ---------------------------------------------------------------------------
__global__ __launch_bounds__(256) void pack_w(const float* __restrict__ kfw,
                                              const float* __restrict__ kbw,
                                              f16* __restrict__ Wt) {
    unsigned idx = blockIdx.x * 256 + threadIdx.x;   // over 2*2048*1024
    int k    = idx & 1023;
    int colp = (idx >> 10) & 2047;
    int d    = idx >> 21;
    int cg = colp >> 6, g = (colp >> 4) & 3, ci = colp & 15;
    int n = cg * 16 + ci;
    const float* K = d ? kbw : kfw;
    Wt[idx] = (f16)K[(size_t)k * 2048 + g * 512 + n];
}

// ---------------------------------------------------------------------------
// Pack W1: W1t[col][k] fp16, k padded 3073 -> 3136 with zeros
// ---------------------------------------------------------------------------
__global__ __launch_bounds__(256) void pack_w1(const float* __restrict__ W1,
                                               f16* __restrict__ W1t) {
    int idx = blockIdx.x * 256 + threadIdx.x;        // over 512*3136
    if (idx >= 512 * HC_K) return;
    int k = idx % HC_K, c = idx / HC_K;
    W1t[idx] = (k < 3073) ? (f16)W1[(size_t)k * MDIM + c] : (f16)0.0f;
}

// ---------------------------------------------------------------------------
// Deterministic rank-sort of the 2048 (input,row) pairs by seqlen DESC
// (ties broken by original index). perm[rank]=row, inv[row]=rank.
// Acnt[t] = #rows with s > t  (active-prefix length at step t).
// ---------------------------------------------------------------------------
__global__ __launch_bounds__(256) void sort_rows(const int* __restrict__ sl1,
                                                 const int* __restrict__ sl2,
                                                 int* __restrict__ perm,
                                                 int* __restrict__ inv,
                                                 int* __restrict__ Acnt) {
    __shared__ int s_sh[ROWS];
    int tid = threadIdx.x;
    for (int i = tid; i < ROWS; i += 256) {
        int b = i & (BATCH - 1);
        s_sh[i] = (i < BATCH) ? sl1[b] : sl2[b];
    }
    __syncthreads();
    int i = blockIdx.x * 256 + tid;
    int si = s_sh[i];
    int rank = 0;
    for (int j = 0; j < ROWS; ++j) {
        int sj = s_sh[j];
        rank += (sj > si) || (sj == si && j < i);
    }
    perm[rank] = i;
    inv[i] = rank;
    if (blockIdx.x == 0 && tid < SEQL) {
        int c = 0;
        for (int j = 0; j < ROWS; ++j) c += (s_sh[j] > tid);
        Acnt[tid] = c;
    }
}

// ---------------------------------------------------------------------------
// One LSTM timestep (both dirs, rows sorted by seqlen desc). 128x128 tile,
// BK=64, 4 waves, MFMA 16x16x32 f16, 2-phase double-buffered staging.
// Row-tiles beyond the active prefix exit immediately. Masked rows in the
// straddle tile are computed but not written (final h read via parity).
// ---------------------------------------------------------------------------
__global__ __launch_bounds__(256, 2) void lstm_step(
    int t,
    const int* __restrict__ in1, const int* __restrict__ in2,
    const int* __restrict__ sl1, const int* __restrict__ sl2,
    const int* __restrict__ perm, const int* __restrict__ Acnt,
    const f16* __restrict__ embH,   // [VOCAB][512]
    const f16* __restrict__ Wt,     // [2][2048 col'][1024 k]
    const float* __restrict__ bfw, const float* __restrict__ bbw,
    const f16* __restrict__ hin,    // [2][2048][512] physical(sorted) rows
    f16* __restrict__ hout,
    float* __restrict__ cbuf)       // [2][2048][512] fp32
{
    const int by  = blockIdx.y;    // row tile (0..15)
    if (by * 128 >= Acnt[t]) return;   // whole tile inactive
    const int dir = blockIdx.z;
    const int bx  = blockIdx.x;    // col tile (0..15)
    const int tid = threadIdx.x;
    const int l = tid & 63, w = tid >> 6;

    __shared__ f16 Atile[2][128 * 64];   // 16 KB each
    __shared__ f16 Btile[2][128 * 64];
    __shared__ int toks[128];
    __shared__ int slens[128];

    if (tid < 128) {
        int r = perm[by * 128 + tid];       // original (input,row) id
        int b = r & (BATCH - 1);
        const int* inp = (r < BATCH) ? in1 : in2;
        int s = (r < BATCH) ? sl1[b] : sl2[b];
        int tt = t;
        if (dir == 1) tt = (t < s) ? (s - 1 - t) : t;
        toks[tid]  = inp[b * SEQL + tt];
        slens[tid] = s;
    }
    __syncthreads();

    // staging: thread covers rows {r*32 + w*8 + (l>>3)}, 16B k-chunk kg
    const int kg8 = (((l & 7) ^ ((l >> 3) & 7))) * 8;   // swizzled k offset (f16)
    int aoffX[4]; int hoff[4]; size_t boff[4]; int dst[4];
#pragma unroll
    for (int r = 0; r < 4; ++r) {
        int row = r * 32 + w * 8 + (l >> 3);
        aoffX[r] = toks[row] * 512 + kg8;
        hoff[r]  = ((dir * ROWS + by * 128 + row) << 9) + kg8;
        boff[r]  = ((size_t)(dir * 2048 + bx * 128 + row) << 10) + kg8;
        dst[r]   = (r * 32 + w * 8) * 64;    // wave-uniform LDS base (f16 units)
    }

    f32x4 acc[4][4];
#pragma unroll
    for (int i = 0; i < 4; ++i)
#pragma unroll
        for (int j = 0; j < 4; ++j) acc[i][j] = (f32x4){0.f, 0.f, 0.f, 0.f};

    const int wr = w >> 1, wc = w & 1;

    // prologue: stage k-tile 0 into buf 0
#pragma unroll
    for (int r = 0; r < 4; ++r) {
        glds16(embH + aoffX[r], &Atile[0][dst[r]]);
        glds16(Wt + boff[r], &Btile[0][dst[r]]);
    }
    __syncthreads();

    int cur = 0;
    for (int kt = 0; kt < 16; ++kt) {
        // ---- prefetch next k-tile into the other buffer
        if (kt < 15) {
            const int kn = kt + 1;
#pragma unroll
            for (int r = 0; r < 4; ++r) {
                const f16* asrc = (kn < 8) ? (embH + aoffX[r] + kn * 64)
                                           : (hin + hoff[r] + (kn - 8) * 64);
                glds16(asrc, &Atile[cur ^ 1][dst[r]]);
                glds16(Wt + boff[r] + kn * 64, &Btile[cur ^ 1][dst[r]]);
            }
        }
        // ---- compute current tile
#pragma unroll
        for (int kk = 0; kk < 2; ++kk) {
            f16x8 af[4], bv[4];
            const int slot = (l >> 4) + kk * 4;
#pragma unroll
            for (int fm = 0; fm < 4; ++fm) {
                int row = wr * 64 + fm * 16 + (l & 15);
                af[fm] = *(const f16x8*)&Atile[cur][row * 64 + (slot ^ (row & 7)) * 8];
            }
#pragma unroll
            for (int fn = 0; fn < 4; ++fn) {
                int col = wc * 64 + fn * 16 + (l & 15);
                bv[fn] = *(const f16x8*)&Btile[cur][col * 64 + (slot ^ (col & 7)) * 8];
            }
#pragma unroll
            for (int fm = 0; fm < 4; ++fm)
#pragma unroll
                for (int fn = 0; fn < 4; ++fn)
                    acc[fm][fn] = __builtin_amdgcn_mfma_f32_16x16x32_f16(
                        af[fm], bv[fn], acc[fm][fn], 0, 0, 0);
        }
        __syncthreads();   // drains prefetch vmcnt + guards buffer swap
        cur ^= 1;
    }

    // ---- fused LSTM epilogue: lane owns cell = bx*32 + wc*16 + (l&15),
    //      gate g = fragment fn; rows = wr*64 + fm*16 + (l>>4)*4 + reg
    const float* bias = dir ? bbw : bfw;
    const int cell = bx * 32 + wc * 16 + (l & 15);
    float bg[4];
#pragma unroll
    for (int g = 0; g < 4; ++g) bg[g] = bias[g * 512 + cell];

#pragma unroll
    for (int fm = 0; fm < 4; ++fm) {
#pragma unroll
        for (int reg = 0; reg < 4; ++reg) {
            int rl = wr * 64 + fm * 16 + (l >> 4) * 4 + reg;
            if (t < slens[rl]) {
                size_t idx = ((size_t)(dir * ROWS + by * 128 + rl) << 9) + cell;
                float gi = acc[fm][0][reg] + bg[0];
                float gj = acc[fm][1][reg] + bg[1];
                float gf = acc[fm][2][reg] + bg[2];
                float go = acc[fm][3][reg] + bg[3];
                float cold = cbuf[idx];
                float cn = cold * sigf(gf + 1.0f) + sigf(gi) * tanh_fast(gj);
                float hn = tanh_fast(cn) * sigf(go);
                cbuf[idx] = cn;
                hout[idx] = (f16)hn;
            }
        }
    }
}

// ---------------------------------------------------------------------------
// Build h_combined fp16 [1024][3136] = [h1, h2, dist, h1*h2, 0-pad].
// Final h of row r lives in parity buffer (s_r & 1) at sorted position inv[r].
// ---------------------------------------------------------------------------
__global__ __launch_bounds__(256) void build_hc(const f16* __restrict__ hbuf0,
                                                const f16* __restrict__ hbuf1,
                                                const int* __restrict__ sl1,
                                                const int* __restrict__ sl2,
                                                const int* __restrict__ inv,
                                                f16* __restrict__ hc) {
    int b = blockIdx.x;
    int tid = threadIdx.x;
    __shared__ float red[256];
    int s1 = sl1[b], s2 = sl2[b];
    int p1 = inv[b], p2 = inv[BATCH + b];
    const f16* hf1 = (s1 & 1) ? hbuf1 : hbuf0;
    const f16* hf2 = (s2 & 1) ? hbuf1 : hbuf0;
    float d = 0.0f;
    size_t base = (size_t)b * HC_K;
    for (int k = tid; k < 1024; k += 256) {
        int dir = k >> 9, kk = k & 511;
        float h1 = (float)hf1[((size_t)(dir * ROWS + p1) << 9) + kk];
        float h2 = (float)hf2[((size_t)(dir * ROWS + p2) << 9) + kk];
        hc[base + k]        = (f16)h1;
        hc[base + 1024 + k] = (f16)h2;
        hc[base + 2049 + k] = (f16)(h1 * h2);
        float df = h1 - h2;
        d += df * df;
    }
    red[tid] = d;
    __syncthreads();
    for (int s = 128; s > 0; s >>= 1) {
        if (tid < s) red[tid] += red[tid + s];
        __syncthreads();
    }
    if (tid == 0) hc[base + 2048] = (f16)red[0];
    if (tid < HC_K - 3073) hc[base + 3073 + tid] = (f16)0.0f;
}

// ---------------------------------------------------------------------------
// e1 = relu(hc @ W1 + b1)   fp16 MFMA, 64x64 tile, BK=64, 4 waves (2x2),
// 2-phase double-buffered staging. K = 3136 (49 tiles).
// ---------------------------------------------------------------------------
__global__ __launch_bounds__(256) void mlp1(const f16* __restrict__ hc,
                                            const f16* __restrict__ W1t,
                                            const float* __restrict__ b1,
                                            float* __restrict__ e1) {
    const int bx = blockIdx.x, by = blockIdx.y, tid = threadIdx.x;
    const int l = tid & 63, w = tid >> 6;
    __shared__ f16 Atile[2][64 * 64];   // 8 KB each
    __shared__ f16 Btile[2][64 * 64];

    const int kg8 = (((l & 7) ^ ((l >> 3) & 7))) * 8;
    size_t aoff[2], boff[2]; int dst[2];
#pragma unroll
    for (int g = 0; g < 2; ++g) {
        int row = g * 32 + w * 8 + (l >> 3);
        aoff[g] = (size_t)(by * 64 + row) * HC_K + kg8;
        boff[g] = (size_t)(bx * 64 + row) * HC_K + kg8;
        dst[g]  = (g * 32 + w * 8) * 64;
    }

    f32x4 acc[2][2];
#pragma unroll
    for (int i = 0; i < 2; ++i)
#pragma unroll
        for (int j = 0; j < 2; ++j) acc[i][j] = (f32x4){0.f, 0.f, 0.f, 0.f};

    const int wr = w >> 1, wc = w & 1;

#pragma unroll
    for (int g = 0; g < 2; ++g) {
        glds16(hc + aoff[g], &Atile[0][dst[g]]);
        glds16(W1t + boff[g], &Btile[0][dst[g]]);
    }
    __syncthreads();

    int cur = 0;
    for (int kt = 0; kt < HC_K / 64; ++kt) {
        if (kt < HC_K / 64 - 1) {
            const int kn = (kt + 1) * 64;
#pragma unroll
            for (int g = 0; g < 2; ++g) {
                glds16(hc + aoff[g] + kn, &Atile[cur ^ 1][dst[g]]);
                glds16(W1t + boff[g] + kn, &Btile[cur ^ 1][dst[g]]);
            }
        }
#pragma unroll
        for (int kk = 0; kk < 2; ++kk) {
            f16x8 af[2], bv[2];
            const int slot = (l >> 4) + kk * 4;
#pragma unroll
            for (int fm = 0; fm < 2; ++fm) {
                int row = wr * 32 + fm * 16 + (l & 15);
                af[fm] = *(const f16x8*)&Atile[cur][row * 64 + (slot ^ (row & 7)) * 8];
            }
#pragma unroll
            for (int fn = 0; fn < 2; ++fn) {
                int col = wc * 32 + fn * 16 + (l & 15);
                bv[fn] = *(const f16x8*)&Btile[cur][col * 64 + (slot ^ (col & 7)) * 8];
            }
#pragma unroll
            for (int fm = 0; fm < 2; ++fm)
#pragma unroll
                for (int fn = 0; fn < 2; ++fn)
                    acc[fm][fn] = __builtin_amdgcn_mfma_f32_16x16x32_f16(
                        af[fm], bv[fn], acc[fm][fn], 0, 0, 0);
        }
        __syncthreads();
        cur ^= 1;
    }

#pragma unroll
    for (int fm = 0; fm < 2; ++fm) {
#pragma unroll
        for (int fn = 0; fn < 2; ++fn) {
#pragma unroll
            for (int reg = 0; reg < 4; ++reg) {
                int r = by * 64 + wr * 32 + fm * 16 + (l >> 4) * 4 + reg;
                int c = bx * 64 + wc * 32 + fn * 16 + (l & 15);
                float v = acc[fm][fn][reg] + b1[c];
                e1[(size_t)r * MDIM + c] = v > 0.0f ? v : 0.0f;
            }
        }
    }
}

// ---------------------------------------------------------------------------
// preds = e1 @ W2 + b2   [1024 x 512] @ [512 x 2]
// ---------------------------------------------------------------------------
__global__ __launch_bounds__(64) void mlp2(const float* __restrict__ e1,
                                           const float* __restrict__ W2,
                                           const float* __restrict__ b2,
                                           float* __restrict__ out) {
    int b = blockIdx.x, tid = threadIdx.x;
    float p0 = 0.f, p1 = 0.f;
    for (int k = tid; k < 512; k += 64) {
        float e = e1[(size_t)b * MDIM + k];
        p0 += e * W2[2 * k];
        p1 += e * W2[2 * k + 1];
    }
    for (int off = 32; off > 0; off >>= 1) {
        p0 += __shfl_down(p0, off);
        p1 += __shfl_down(p1, off);
    }
    if (tid == 0) {
        out[2 * b]     = p0 + b2[0];
        out[2 * b + 1] = p1 + b2[1];
    }
}

// ---------------------------------------------------------------------------
extern "C" void kernel_launch(void* const* d_in, const int* in_sizes, int n_in,
                              void* d_out, int out_size, void* d_ws, size_t ws_size,
                              hipStream_t stream) {
    (void)in_sizes; (void)n_in; (void)out_size; (void)ws_size;
    const int*   in1 = (const int*)d_in[0];
    const int*   in2 = (const int*)d_in[1];
    const int*   sl1 = (const int*)d_in[2];
    const int*   sl2 = (const int*)d_in[3];
    const float* emb = (const float*)d_in[4];
    const float* kfw = (const float*)d_in[5];
    const float* bfw = (const float*)d_in[6];
    const float* kbw = (const float*)d_in[7];
    const float* bbw = (const float*)d_in[8];
    const float* W1  = (const float*)d_in[9];
    const float* b1  = (const float*)d_in[10];
    const float* W2  = (const float*)d_in[11];
    const float* b2  = (const float*)d_in[12];
    float* out = (float*)d_out;

    char* base = (char*)d_ws;
    f16*   embH = (f16*)base;                      // 51,200,000 B
    f16*   Wt   = (f16*)(base + 51200000);         //  8,388,608 B
    f16*   W1t  = (f16*)(base + 59588608);         //  3,211,264 B
    float* cbuf = (float*)(base + 62799872);       //  8,388,608 B
    f16*   h0   = (f16*)(base + 71188480);         //  4,194,304 B
    f16*   h1   = (f16*)(base + 75382784);         //  4,194,304 B
    f16*   hc   = (f16*)(base + 79577088);         //  6,422,528 B
    float* e1   = (float*)(base + 85999616);       //  2,097,152 B
    int*   perm = (int*)(base + 88096768);         //      8,192 B
    int*   inv  = (int*)(base + 88104960);         //      8,192 B
    int*   Acnt = (int*)(base + 88113152);         //        256 B

    // zero c and h0 (initial state); h1 fully written at step 0 (all active)
    hipMemsetAsync(cbuf, 0, 8388608, stream);
    hipMemsetAsync(h0, 0, 4194304, stream);

    sort_rows<<<ROWS / 256, 256, 0, stream>>>(sl1, sl2, perm, inv, Acnt);
    conv_emb<<<(VOCAB * D_EMB / 8 + 255) / 256, 256, 0, stream>>>(emb, embH, VOCAB * D_EMB / 8);
    pack_w<<<(2 * 2048 * KTOT) / 256, 256, 0, stream>>>(kfw, kbw, Wt);
    pack_w1<<<(512 * HC_K + 255) / 256, 256, 0, stream>>>(W1, W1t);

    for (int t = 0; t < SEQL; ++t) {
        const f16* hi = (t & 1) ? h1 : h0;   // buf[t&1]
        f16*       ho = (t & 1) ? h0 : h1;   // buf[(t+1)&1]
        lstm_step<<<dim3(16, 16, 2), 256, 0, stream>>>(
            t, in1, in2, sl1, sl2, perm, Acnt, embH, Wt, bfw, bbw, hi, ho, cbuf);
    }

    build_hc<<<BATCH, 256, 0, stream>>>(h0, h1, sl1, sl2, inv, hc);
    mlp1<<<dim3(MDIM / 64, BATCH / 64), 256, 0, stream>>>(hc, W1t, b1, e1);
    mlp2<<<BATCH, 64, 0, stream>>>(e1, W2, b2, out);
}